// Round 7
// baseline (371.221 us; speedup 1.0000x reference)
//
#include <hip/hip_runtime.h>
#include <cstdint>

#define IN_F 4096
#define OUT_F 11008
#define NG 32
#define BM 128
#define BN 128
#define BK 64
#define NKT 64
#define NBLK 344   // 86 strips * 4 m-blocks

typedef _Float16 half8 __attribute__((ext_vector_type(8)));
typedef _Float16 h2 __attribute__((ext_vector_type(2)));
typedef float f32x4 __attribute__((ext_vector_type(4)));

__device__ __forceinline__ int dq2(int u0, int u1, h2 sv, h2 bv) {
    // (q | 0x6400) as f16 = 1024+q exactly (q in [0,16)); subtract, then fma
    uint32_t t = ((uint32_t)u0 | ((uint32_t)u1 << 16)) | 0x64006400u;
    h2 v = __builtin_bit_cast(h2, t);
    v = v - (h2){(_Float16)1024.0f, (_Float16)1024.0f};
    v = v * sv + bv;
    return __builtin_bit_cast(int, v);
}

// ---------- prepass: x fp32 -> f16 into d_ws (512*4096 elems, 8/thread) ----
__global__ __launch_bounds__(256) void cvt_x(const float* __restrict__ x,
                                             _Float16* __restrict__ xh) {
    int i = (blockIdx.x * 256 + threadIdx.x) * 8;
    float4 f0 = *(const float4*)(x + i);
    float4 f1 = *(const float4*)(x + i + 4);
    int4 o;
    o.x = __builtin_bit_cast(int, __builtin_amdgcn_cvt_pkrtz(f0.x, f0.y));
    o.y = __builtin_bit_cast(int, __builtin_amdgcn_cvt_pkrtz(f0.z, f0.w));
    o.z = __builtin_bit_cast(int, __builtin_amdgcn_cvt_pkrtz(f1.x, f1.y));
    o.w = __builtin_bit_cast(int, __builtin_amdgcn_cvt_pkrtz(f1.z, f1.w));
    *(int4*)(xh + i) = o;
}

// Static-register macros (lambda array-ref params / dynamic indexing spill —
// proven rounds 2/3). Pasted names parenthesized: q##S##0.x would mis-token.

#define PF_A(kt) do {                                                          \
    const _Float16* _p = xh + (size_t)(m0 + rg) * IN_F + (kt) * BK + c8 * 8;   \
    aP0 = *(const int4*)(_p);                                                  \
    aP1 = *(const int4*)(_p + (size_t)32 * IN_F);                              \
    aP2 = *(const int4*)(_p + (size_t)64 * IN_F);                              \
    aP3 = *(const int4*)(_p + (size_t)96 * IN_F);                              \
} while (0)

#define PF_B(kt, S) do {                                                       \
    const int _g = (kt) >> 1;                                                  \
    const int* _p0 = qw + (size_t)(n0 + rg) * IN_F + (kt) * BK + c8 * 8;       \
    (q##S##0) = ((const int4*)_p0)[0];                                         \
    (q##S##1) = ((const int4*)_p0)[1];                                         \
    (q##S##2) = ((const int4*)(_p0 + (size_t)32 * IN_F))[0];                   \
    (q##S##3) = ((const int4*)(_p0 + (size_t)32 * IN_F))[1];                   \
    (q##S##4) = ((const int4*)(_p0 + (size_t)64 * IN_F))[0];                   \
    (q##S##5) = ((const int4*)(_p0 + (size_t)64 * IN_F))[1];                   \
    (q##S##6) = ((const int4*)(_p0 + (size_t)96 * IN_F))[0];                   \
    (q##S##7) = ((const int4*)(_p0 + (size_t)96 * IN_F))[1];                   \
    (s##S##0) = sc [(size_t)(n0 + rg)      * NG + _g];                         \
    (s##S##1) = sc [(size_t)(n0 + rg + 32) * NG + _g];                         \
    (s##S##2) = sc [(size_t)(n0 + rg + 64) * NG + _g];                         \
    (s##S##3) = sc [(size_t)(n0 + rg + 96) * NG + _g];                         \
    (z##S##0) = zpt[(size_t)(n0 + rg)      * NG + _g];                         \
    (z##S##1) = zpt[(size_t)(n0 + rg + 32) * NG + _g];                         \
    (z##S##2) = zpt[(size_t)(n0 + rg + 64) * NG + _g];                         \
    (z##S##3) = zpt[(size_t)(n0 + rg + 96) * NG + _g];                         \
} while (0)

#define STAGE_A(buf) do {                                                      \
    *(int4*)&As[buf][(rg)      * BK + xo] = aP0;                               \
    *(int4*)&As[buf][(rg + 32) * BK + xo] = aP1;                               \
    *(int4*)&As[buf][(rg + 64) * BK + xo] = aP2;                               \
    *(int4*)&As[buf][(rg + 96) * BK + xo] = aP3;                               \
} while (0)

#define STAGE_B_ROW(buf, S, J, QA, QB) do {                                    \
    float _s = (s##S##J); _Float16 _hs = (_Float16)_s;                         \
    _Float16 _hb = (_Float16)(-(z##S##J) * _s);                                \
    h2 _sv = {_hs, _hs}, _bv = {_hb, _hb};                                     \
    int4 _o;                                                                   \
    _o.x = dq2((QA).x, (QA).y, _sv, _bv);                                      \
    _o.y = dq2((QA).z, (QA).w, _sv, _bv);                                      \
    _o.z = dq2((QB).x, (QB).y, _sv, _bv);                                      \
    _o.w = dq2((QB).z, (QB).w, _sv, _bv);                                      \
    *(int4*)&Bs[buf][(rg + 32 * (J)) * BK + xo] = _o;                          \
} while (0)

#define STAGE_B(buf, S) do {                                                   \
    STAGE_B_ROW(buf, S, 0, (q##S##0), (q##S##1));                              \
    STAGE_B_ROW(buf, S, 1, (q##S##2), (q##S##3));                              \
    STAGE_B_ROW(buf, S, 2, (q##S##4), (q##S##5));                              \
    STAGE_B_ROW(buf, S, 3, (q##S##6), (q##S##7));                              \
} while (0)

__global__ __launch_bounds__(256, 2) void qlin_mfma6(
    const _Float16* __restrict__ xh, const int* __restrict__ qw,
    const float* __restrict__ sc, const float* __restrict__ zpt,
    const float* __restrict__ bias, float* __restrict__ out)
{
    __shared__ __align__(16) _Float16 As[2][BM * BK]; // 16 KB each
    __shared__ __align__(16) _Float16 Bs[2][BN * BK]; // 16 KB each

    const int tid = threadIdx.x;

    // XCD-colocation swizzle: 4 same-strip m-blocks get ids = same (mod 8)
    int L = blockIdx.x, strip, mblk;
    if (L < 320) { int p = L >> 5, i = L & 31; strip = p * 8 + (i & 7); mblk = i >> 3; }
    else         { int i = L - 320;            strip = 80 + (i % 6);    mblk = i / 6; }
    const int m0 = mblk * BM;
    const int n0 = strip * BN;

    const int lane = tid & 63;
    const int w    = tid >> 6;        // 2x2 waves over 128x128
    const int wm   = (w & 1) * 64;
    const int wn   = (w >> 1) * 64;
    const int l16  = lane & 15;
    const int quad = lane >> 4;

    const int c8 = tid & 7;               // 16B granule within 64-elem row
    const int rg = tid >> 3;              // 0..31
    const int xo = (c8 ^ (rg & 7)) << 3;  // XOR-swizzled slot

    int4 aP0, aP1, aP2, aP3;              // A f16 prefetch (dist-1)
    int4 qA0, qA1, qA2, qA3, qA4, qA5, qA6, qA7;   // B set A (dist-2)
    float sA0, sA1, sA2, sA3, zA0, zA1, zA2, zA3;
    int4 qB0, qB1, qB2, qB3, qB4, qB5, qB6, qB7;   // B set B (dist-2)
    float sB0, sB1, sB2, sB3, zB0, zB1, zB2, zB3;

    f32x4 acc[4][4];
#pragma unroll
    for (int mt = 0; mt < 4; ++mt)
#pragma unroll
        for (int nt = 0; nt < 4; ++nt)
            acc[mt][nt] = (f32x4){0.f, 0.f, 0.f, 0.f};

    auto compute = [&](int buf) {
#pragma unroll
        for (int ks = 0; ks < 2; ++ks) {
            half8 a[4], b[4];
            const int ck = ks * 4 + quad;
#pragma unroll
            for (int mt = 0; mt < 4; ++mt) {
                int row = wm + mt * 16 + l16;
                a[mt] = *(const half8*)&As[buf][row * BK + ((ck ^ (row & 7)) << 3)];
            }
#pragma unroll
            for (int nt = 0; nt < 4; ++nt) {
                int row = wn + nt * 16 + l16;
                b[nt] = *(const half8*)&Bs[buf][row * BK + ((ck ^ (row & 7)) << 3)];
            }
#pragma unroll
            for (int mt = 0; mt < 4; ++mt)
#pragma unroll
                for (int nt = 0; nt < 4; ++nt)
                    acc[mt][nt] = __builtin_amdgcn_mfma_f32_16x16x32_f16(
                        a[mt], b[nt], acc[mt][nt], 0, 0, 0);
        }
    };

    // prologue: tile0 staged into buf0; setB holds tile1; setA refilled to tile2
    PF_B(0, A);
    PF_A(0);
    PF_B(1, B);
    STAGE_A(0);
    STAGE_B(0, A);
    PF_A(1);
    PF_B(2, A);
    __syncthreads();

#pragma unroll 1
    for (int kt = 0; kt < NKT; kt += 2) {
        // even: stage kt+1 (aP, setB) into buf1 first (vmcnt wait at iter
        // start => ~2 iterations of latency coverage), then compute buf0
        {
            STAGE_A(1);
            STAGE_B(1, B);
            int ka = kt + 2 < NKT ? kt + 2 : NKT - 1;
            int kb = kt + 3 < NKT ? kt + 3 : NKT - 1;
            PF_A(ka);
            PF_B(kb, B);
        }
        compute(0);
        __syncthreads();
        // odd: stage kt+2 (aP, setA) into buf0, compute buf1
        if (kt + 2 < NKT) {
            STAGE_A(0);
            STAGE_B(0, A);
            int ka = kt + 3 < NKT ? kt + 3 : NKT - 1;
            int kb = kt + 4 < NKT ? kt + 4 : NKT - 1;
            PF_A(ka);
            PF_B(kb, A);
        }
        compute(1);
        __syncthreads();
    }

    // epilogue: C/D layout col = lane&15, row = quad*4 + r
#pragma unroll
    for (int nt = 0; nt < 4; ++nt) {
        int n = n0 + wn + nt * 16 + l16;
        float bv = bias[n];
#pragma unroll
        for (int mt = 0; mt < 4; ++mt) {
            int mb = m0 + wm + mt * 16 + quad * 4;
#pragma unroll
            for (int r = 0; r < 4; ++r)
                out[(size_t)(mb + r) * OUT_F + n] = acc[mt][nt][r] + bv;
        }
    }
}

// ---------- fallback (proven round-4 kernel): fp32 x, dist-1, BN=64 --------
#define FBM 128
#define FBN 64
__global__ __launch_bounds__(256, 3) void qlin_mfma4(
    const float* __restrict__ x, const int* __restrict__ qw,
    const float* __restrict__ sc, const float* __restrict__ zpt,
    const float* __restrict__ bias, float* __restrict__ out)
{
    __shared__ __align__(16) _Float16 As[2][FBM * BK];
    __shared__ __align__(16) _Float16 Bs[2][FBN * BK];

    const int tid = threadIdx.x;
    int L = blockIdx.x, strip, mblk;
    if (L < 672) { int p = L >> 5, i = L & 31; strip = p * 8 + (i & 7); mblk = i >> 3; }
    else         { int i = L - 672;            strip = 168 + (i & 3);   mblk = i >> 2; }
    const int m0 = mblk * FBM;
    const int n0 = strip * FBN;

    const int lane = tid & 63;
    const int w    = tid >> 6;
    const int wm   = (w & 1) * 64;
    const int wn   = (w >> 1) * 32;
    const int l16  = lane & 15;
    const int quad = lane >> 4;

    const int c8 = tid & 7;
    const int rg = tid >> 3;

    float4 aP[8];
    int4   bP[4];
    float  sP[2], zP[2];

    auto pf = [&](int kt) {
        const int k0 = kt * BK;
        const int g  = kt >> 1;
#pragma unroll
        for (int j = 0; j < 4; ++j) {
            int row = rg + 32 * j;
            const float4* p = (const float4*)(x + (size_t)(m0 + row) * IN_F + k0 + c8 * 8);
            aP[2 * j]     = p[0];
            aP[2 * j + 1] = p[1];
        }
#pragma unroll
        for (int j = 0; j < 2; ++j) {
            int row = n0 + rg + 32 * j;
            const int4* p = (const int4*)(qw + (size_t)row * IN_F + k0 + c8 * 8);
            bP[2 * j]     = p[0];
            bP[2 * j + 1] = p[1];
            sP[j] = sc [(size_t)row * NG + g];
            zP[j] = zpt[(size_t)row * NG + g];
        }
    };

    auto stage = [&](int buf) {
#pragma unroll
        for (int j = 0; j < 4; ++j) {
            int row = rg + 32 * j;
            float4 f0 = aP[2 * j], f1 = aP[2 * j + 1];
            int4 o;
            o.x = __builtin_bit_cast(int, __builtin_amdgcn_cvt_pkrtz(f0.x, f0.y));
            o.y = __builtin_bit_cast(int, __builtin_amdgcn_cvt_pkrtz(f0.z, f0.w));
            o.z = __builtin_bit_cast(int, __builtin_amdgcn_cvt_pkrtz(f1.x, f1.y));
            o.w = __builtin_bit_cast(int, __builtin_amdgcn_cvt_pkrtz(f1.z, f1.w));
            *(int4*)&As[buf][row * BK + ((c8 ^ (row & 7)) << 3)] = o;
        }
#pragma unroll
        for (int j = 0; j < 2; ++j) {
            int row = rg + 32 * j;
            float sf = sP[j];
            _Float16 sh = (_Float16)sf;
            _Float16 bh = (_Float16)(-zP[j] * sf);
            h2 sv = {sh, sh}, bv = {bh, bh};
            int4 q0 = bP[2 * j], q1 = bP[2 * j + 1];
            int4 o;
            o.x = dq2(q0.x, q0.y, sv, bv);
            o.y = dq2(q0.z, q0.w, sv, bv);
            o.z = dq2(q1.x, q1.y, sv, bv);
            o.w = dq2(q1.z, q1.w, sv, bv);
            *(int4*)&Bs[buf][row * BK + ((c8 ^ (row & 7)) << 3)] = o;
        }
    };

    f32x4 acc[4][2];
#pragma unroll
    for (int mt = 0; mt < 4; ++mt)
#pragma unroll
        for (int nt = 0; nt < 2; ++nt)
            acc[mt][nt] = (f32x4){0.f, 0.f, 0.f, 0.f};

    auto compute = [&](int buf) {
#pragma unroll
        for (int ks = 0; ks < 2; ++ks) {
            half8 a[4], b[2];
            const int ck = ks * 4 + quad;
#pragma unroll
            for (int mt = 0; mt < 4; ++mt) {
                int row = wm + mt * 16 + l16;
                a[mt] = *(const half8*)&As[buf][row * BK + ((ck ^ (row & 7)) << 3)];
            }
#pragma unroll
            for (int nt = 0; nt < 2; ++nt) {
                int row = wn + nt * 16 + l16;
                b[nt] = *(const half8*)&Bs[buf][row * BK + ((ck ^ (row & 7)) << 3)];
            }
#pragma unroll
            for (int mt = 0; mt < 4; ++mt)
#pragma unroll
                for (int nt = 0; nt < 2; ++nt)
                    acc[mt][nt] = __builtin_amdgcn_mfma_f32_16x16x32_f16(
                        a[mt], b[nt], acc[mt][nt], 0, 0, 0);
        }
    };

    pf(0);
    stage(0);
    __syncthreads();

#pragma unroll 1
    for (int kt = 0; kt < NKT; ++kt) {
        const int buf = kt & 1;
        if (kt + 1 < NKT) {
            pf(kt + 1);
            compute(buf);
            stage(buf ^ 1);
            __syncthreads();
        } else {
            compute(buf);
        }
    }

#pragma unroll
    for (int nt = 0; nt < 2; ++nt) {
        int n = n0 + wn + nt * 16 + l16;
        float bv = bias[n];
#pragma unroll
        for (int mt = 0; mt < 4; ++mt) {
            int mb = m0 + wm + mt * 16 + quad * 4;
#pragma unroll
            for (int r = 0; r < 4; ++r)
                out[(size_t)(mb + r) * OUT_F + n] = acc[mt][nt][r] + bv;
        }
    }
}

extern "C" void kernel_launch(void* const* d_in, const int* in_sizes, int n_in,
                              void* d_out, int out_size, void* d_ws, size_t ws_size,
                              hipStream_t stream) {
    const float* x    = (const float*)d_in[0];
    const int*   qw   = (const int*)d_in[1];
    const float* scp  = (const float*)d_in[2];
    const float* zpp  = (const float*)d_in[3];
    const float* bias = (const float*)d_in[4];
    float* out = (float*)d_out;
    (void)in_sizes; (void)n_in; (void)out_size;

    const size_t need = (size_t)512 * IN_F * sizeof(_Float16); // 4 MB
    if (ws_size >= need) {
        _Float16* xh = (_Float16*)d_ws;
        cvt_x<<<dim3(1024), dim3(256), 0, stream>>>(x, xh);
        qlin_mfma6<<<dim3(NBLK), dim3(256), 0, stream>>>(xh, qw, scp, zpp, bias, out);
    } else {
        qlin_mfma4<<<dim3(688), dim3(256), 0, stream>>>(x, qw, scp, zpp, bias, out);
    }
}

// Round 8
// 363.896 us; speedup vs baseline: 1.0201x; 1.0201x over previous
//
#include <hip/hip_runtime.h>
#include <cstdint>

#define IN_F 4096
#define OUT_F 11008
#define NG 32
#define BM 128
#define BN 64
#define BK 64
#define NKT 64
#define NBLK 688   // 172 strips * 4 m-blocks

typedef _Float16 half8 __attribute__((ext_vector_type(8)));
typedef _Float16 h2 __attribute__((ext_vector_type(2)));
typedef float f32x4 __attribute__((ext_vector_type(4)));

__device__ __forceinline__ int dq2(int u0, int u1, h2 sv, h2 bv) {
    // (q | 0x6400) as f16 = 1024+q exactly (q in [0,16)); subtract, then fma
    uint32_t t = ((uint32_t)u0 | ((uint32_t)u1 << 16)) | 0x64006400u;
    h2 v = __builtin_bit_cast(h2, t);
    v = v - (h2){(_Float16)1024.0f, (_Float16)1024.0f};
    v = v * sv + bv;
    return __builtin_bit_cast(int, v);
}

// ---- prepass: x fp32 -> f16 in MFMA-A-fragment order ----------------------
// xt layout: [m16 (32)][kc (128)][lane (64)][8 halfs], where for fragment
// (m16, kc): lane = (m&15) | ((k>>3)&3)<<4, elem = k&7, k = kc*32 + ...
// => a wave's A-frag load is ONE contiguous 1KB global_load_dwordx4.
__global__ __launch_bounds__(256) void cvt_xt(const float* __restrict__ x,
                                              _Float16* __restrict__ xt) {
    int idx = blockIdx.x * 256 + threadIdx.x;   // 262144 chunks of 8
    int lane = idx & 63;
    int l16 = lane & 15, quad = lane >> 4;
    int kc = (idx >> 6) & 127;
    int m16 = idx >> 13;
    int m = m16 * 16 + l16;
    int k = kc * 32 + quad * 8;
    const float4* p = (const float4*)(x + (size_t)m * IN_F + k);
    float4 f0 = p[0], f1 = p[1];
    int4 o;
    o.x = __builtin_bit_cast(int, __builtin_amdgcn_cvt_pkrtz(f0.x, f0.y));
    o.y = __builtin_bit_cast(int, __builtin_amdgcn_cvt_pkrtz(f0.z, f0.w));
    o.z = __builtin_bit_cast(int, __builtin_amdgcn_cvt_pkrtz(f1.x, f1.y));
    o.w = __builtin_bit_cast(int, __builtin_amdgcn_cvt_pkrtz(f1.z, f1.w));
    *(int4*)(xt + (size_t)idx * 8) = o;
}

// Static-register macros (dynamic indexing / lambda array-ref params spill —
// proven rounds 2/3). Pasted names parenthesized (pp-number trap, round 5).

// A frags for tile kt into set S (C or N): frag f = mt*2+ks, constant-indexed
#define PF_A(kt, S) do {                                                       \
    const _Float16* _pa = xt + (((size_t)am16 * 128 + (size_t)(kt) * 2) * 64   \
                                + lane) * 8;                                   \
    a##S[0] = *(const int4*)(_pa);                                             \
    a##S[1] = *(const int4*)(_pa + 512);                                       \
    a##S[2] = *(const int4*)(_pa + 65536);                                     \
    a##S[3] = *(const int4*)(_pa + 65536 + 512);                               \
    a##S[4] = *(const int4*)(_pa + 131072);                                    \
    a##S[5] = *(const int4*)(_pa + 131072 + 512);                              \
    a##S[6] = *(const int4*)(_pa + 196608);                                    \
    a##S[7] = *(const int4*)(_pa + 196608 + 512);                              \
} while (0)

#define PF_B(kt, S) do {                                                       \
    const int _g = (kt) >> 1;                                                  \
    const int* _p0 = qw + (size_t)(n0 + rg) * IN_F + (kt) * BK + c8 * 8;       \
    (q##S##0) = ((const int4*)_p0)[0];                                         \
    (q##S##1) = ((const int4*)_p0)[1];                                         \
    (q##S##2) = ((const int4*)(_p0 + (size_t)32 * IN_F))[0];                   \
    (q##S##3) = ((const int4*)(_p0 + (size_t)32 * IN_F))[1];                   \
    (s##S##0) = sc [(size_t)(n0 + rg)      * NG + _g];                         \
    (s##S##1) = sc [(size_t)(n0 + rg + 32) * NG + _g];                         \
    (z##S##0) = zpt[(size_t)(n0 + rg)      * NG + _g];                         \
    (z##S##1) = zpt[(size_t)(n0 + rg + 32) * NG + _g];                         \
} while (0)

#define STAGE_B(buf, S) do {                                                   \
    float _s0 = (s##S##0); _Float16 _h0 = (_Float16)_s0;                       \
    _Float16 _b0 = (_Float16)(-(z##S##0) * _s0);                               \
    h2 _sv0 = {_h0, _h0}, _bv0 = {_b0, _b0};                                   \
    int4 _o;                                                                   \
    _o.x = dq2((q##S##0).x, (q##S##0).y, _sv0, _bv0);                          \
    _o.y = dq2((q##S##0).z, (q##S##0).w, _sv0, _bv0);                          \
    _o.z = dq2((q##S##1).x, (q##S##1).y, _sv0, _bv0);                          \
    _o.w = dq2((q##S##1).z, (q##S##1).w, _sv0, _bv0);                          \
    *(int4*)&Bs[buf][(rg) * BK + xo] = _o;                                     \
    float _s1 = (s##S##1); _Float16 _h1 = (_Float16)_s1;                       \
    _Float16 _b1 = (_Float16)(-(z##S##1) * _s1);                               \
    h2 _sv1 = {_h1, _h1}, _bv1 = {_b1, _b1};                                   \
    _o.x = dq2((q##S##2).x, (q##S##2).y, _sv1, _bv1);                          \
    _o.y = dq2((q##S##2).z, (q##S##2).w, _sv1, _bv1);                          \
    _o.z = dq2((q##S##3).x, (q##S##3).y, _sv1, _bv1);                          \
    _o.w = dq2((q##S##3).z, (q##S##3).w, _sv1, _bv1);                          \
    *(int4*)&Bs[buf][(rg + 32) * BK + xo] = _o;                                \
} while (0)

__global__ __launch_bounds__(256, 3) void qlin_mfma7(
    const _Float16* __restrict__ xt, const int* __restrict__ qw,
    const float* __restrict__ sc, const float* __restrict__ zpt,
    const float* __restrict__ bias, float* __restrict__ out)
{
    // B-only LDS: 16 KB total (A comes straight from L2 in fragment order)
    __shared__ __align__(16) _Float16 Bs[2][BN * BK];

    const int tid = threadIdx.x;

    // XCD-colocation swizzle (proven: FETCH 936->175 MB)
    int L = blockIdx.x, strip, mblk;
    if (L < 672) { int p = L >> 5, i = L & 31; strip = p * 8 + (i & 7); mblk = i >> 3; }
    else         { int i = L - 672;            strip = 168 + (i & 3);   mblk = i >> 2; }
    const int m0 = mblk * BM;
    const int n0 = strip * BN;

    const int lane = tid & 63;
    const int w    = tid >> 6;        // 4 waves: 2x2 over 128x64
    const int wm   = (w & 1) * 64;
    const int wn   = (w >> 1) * 32;
    const int l16  = lane & 15;
    const int quad = lane >> 4;
    const int am16 = (m0 + wm) >> 4;  // this wave's A m16-tile base

    const int c8 = tid & 7;               // 16B granule within 64-elem row
    const int rg = tid >> 3;              // 0..31
    const int xo = (c8 ^ (rg & 7)) << 3;  // XOR-swizzled slot

    int4 aC[8], aN[8];                                 // A frag sets (dist-1)
    int4 qA0, qA1, qA2, qA3; float sA0, sA1, zA0, zA1; // B set A (dist-2)
    int4 qB0, qB1, qB2, qB3; float sB0, sB1, zB0, zB1; // B set B (dist-2)

    f32x4 acc[4][2];
#pragma unroll
    for (int mt = 0; mt < 4; ++mt)
#pragma unroll
        for (int nt = 0; nt < 2; ++nt)
            acc[mt][nt] = (f32x4){0.f, 0.f, 0.f, 0.f};

    auto computeC = [&](int buf) {
#pragma unroll
        for (int ks = 0; ks < 2; ++ks) {
            half8 b[2];
            const int ck = ks * 4 + quad;
#pragma unroll
            for (int nt = 0; nt < 2; ++nt) {
                int row = wn + nt * 16 + l16;
                b[nt] = *(const half8*)&Bs[buf][row * BK + ((ck ^ (row & 7)) << 3)];
            }
#pragma unroll
            for (int mt = 0; mt < 4; ++mt)
#pragma unroll
                for (int nt = 0; nt < 2; ++nt)
                    acc[mt][nt] = __builtin_amdgcn_mfma_f32_16x16x32_f16(
                        __builtin_bit_cast(half8, aC[mt * 2 + ks]), b[nt],
                        acc[mt][nt], 0, 0, 0);
        }
    };
    auto computeN = [&](int buf) {
#pragma unroll
        for (int ks = 0; ks < 2; ++ks) {
            half8 b[2];
            const int ck = ks * 4 + quad;
#pragma unroll
            for (int nt = 0; nt < 2; ++nt) {
                int row = wn + nt * 16 + l16;
                b[nt] = *(const half8*)&Bs[buf][row * BK + ((ck ^ (row & 7)) << 3)];
            }
#pragma unroll
            for (int mt = 0; mt < 4; ++mt)
#pragma unroll
                for (int nt = 0; nt < 2; ++nt)
                    acc[mt][nt] = __builtin_amdgcn_mfma_f32_16x16x32_f16(
                        __builtin_bit_cast(half8, aN[mt * 2 + ks]), b[nt],
                        acc[mt][nt], 0, 0, 0);
        }
    };

    // prologue: buf0 = tile0 (from setA); qB = tile1; qA refilled to tile2; aC = tile0
    PF_B(0, A);
    PF_B(1, B);
    PF_A(0, C);
    STAGE_B(0, A);
    PF_B(2, A);
    __syncthreads();

#pragma unroll 1
    for (int kt = 0; kt < NKT; kt += 2) {
        // even tile kt: stage tile kt+1 (setB) into buf1 first, then compute buf0+aC
        STAGE_B(1, B);
        {
            int kb = kt + 3 < NKT ? kt + 3 : NKT - 1;
            PF_B(kb, B);
            int ka = kt + 1 < NKT ? kt + 1 : NKT - 1;
            PF_A(ka, N);
        }
        computeC(0);
        __syncthreads();
        // odd tile kt+1: stage tile kt+2 (setA) into buf0, compute buf1+aN
        if (kt + 2 < NKT) {
            STAGE_B(0, A);
            int kb = kt + 4 < NKT ? kt + 4 : NKT - 1;
            PF_B(kb, A);
            PF_A(kt + 2, C);
        }
        computeN(1);
        __syncthreads();
    }

    // epilogue: C/D layout col = lane&15, row = quad*4 + r
#pragma unroll
    for (int nt = 0; nt < 2; ++nt) {
        int n = n0 + wn + nt * 16 + l16;
        float bv = bias[n];
#pragma unroll
        for (int mt = 0; mt < 4; ++mt) {
            int mb = m0 + wm + mt * 16 + quad * 4;
#pragma unroll
            for (int r = 0; r < 4; ++r)
                out[(size_t)(mb + r) * OUT_F + n] = acc[mt][nt][r] + bv;
        }
    }
}

// ---------- fallback (proven round-4 kernel): fp32 x, dist-1, no ws --------
__global__ __launch_bounds__(256, 3) void qlin_mfma4(
    const float* __restrict__ x, const int* __restrict__ qw,
    const float* __restrict__ sc, const float* __restrict__ zpt,
    const float* __restrict__ bias, float* __restrict__ out)
{
    __shared__ __align__(16) _Float16 As[2][BM * BK];
    __shared__ __align__(16) _Float16 Bs[2][BN * BK];

    const int tid = threadIdx.x;
    int L = blockIdx.x, strip, mblk;
    if (L < 672) { int p = L >> 5, i = L & 31; strip = p * 8 + (i & 7); mblk = i >> 3; }
    else         { int i = L - 672;            strip = 168 + (i & 3);   mblk = i >> 2; }
    const int m0 = mblk * BM;
    const int n0 = strip * BN;

    const int lane = tid & 63;
    const int w    = tid >> 6;
    const int wm   = (w & 1) * 64;
    const int wn   = (w >> 1) * 32;
    const int l16  = lane & 15;
    const int quad = lane >> 4;

    const int c8 = tid & 7;
    const int rg = tid >> 3;

    float4 aP[8];
    int4   bP[4];
    float  sP[2], zP[2];

    auto pf = [&](int kt) {
        const int k0 = kt * BK;
        const int g  = kt >> 1;
#pragma unroll
        for (int j = 0; j < 4; ++j) {
            int row = rg + 32 * j;
            const float4* p = (const float4*)(x + (size_t)(m0 + row) * IN_F + k0 + c8 * 8);
            aP[2 * j]     = p[0];
            aP[2 * j + 1] = p[1];
        }
#pragma unroll
        for (int j = 0; j < 2; ++j) {
            int row = n0 + rg + 32 * j;
            const int4* p = (const int4*)(qw + (size_t)row * IN_F + k0 + c8 * 8);
            bP[2 * j]     = p[0];
            bP[2 * j + 1] = p[1];
            sP[j] = sc [(size_t)row * NG + g];
            zP[j] = zpt[(size_t)row * NG + g];
        }
    };

    auto stage = [&](int buf) {
#pragma unroll
        for (int j = 0; j < 4; ++j) {
            int row = rg + 32 * j;
            float4 f0 = aP[2 * j], f1 = aP[2 * j + 1];
            int4 o;
            o.x = __builtin_bit_cast(int, __builtin_amdgcn_cvt_pkrtz(f0.x, f0.y));
            o.y = __builtin_bit_cast(int, __builtin_amdgcn_cvt_pkrtz(f0.z, f0.w));
            o.z = __builtin_bit_cast(int, __builtin_amdgcn_cvt_pkrtz(f1.x, f1.y));
            o.w = __builtin_bit_cast(int, __builtin_amdgcn_cvt_pkrtz(f1.z, f1.w));
            *(int4*)&As[buf][row * BK + ((c8 ^ (row & 7)) << 3)] = o;
        }
#pragma unroll
        for (int j = 0; j < 2; ++j) {
            int row = rg + 32 * j;
            float sf = sP[j];
            _Float16 sh = (_Float16)sf;
            _Float16 bh = (_Float16)(-zP[j] * sf);
            h2 sv = {sh, sh}, bv = {bh, bh};
            int4 q0 = bP[2 * j], q1 = bP[2 * j + 1];
            int4 o;
            o.x = dq2(q0.x, q0.y, sv, bv);
            o.y = dq2(q0.z, q0.w, sv, bv);
            o.z = dq2(q1.x, q1.y, sv, bv);
            o.w = dq2(q1.z, q1.w, sv, bv);
            *(int4*)&Bs[buf][row * BK + ((c8 ^ (row & 7)) << 3)] = o;
        }
    };

    f32x4 acc[4][2];
#pragma unroll
    for (int mt = 0; mt < 4; ++mt)
#pragma unroll
        for (int nt = 0; nt < 2; ++nt)
            acc[mt][nt] = (f32x4){0.f, 0.f, 0.f, 0.f};

    auto compute = [&](int buf) {
#pragma unroll
        for (int ks = 0; ks < 2; ++ks) {
            half8 a[4], b[2];
            const int ck = ks * 4 + quad;
#pragma unroll
            for (int mt = 0; mt < 4; ++mt) {
                int row = wm + mt * 16 + l16;
                a[mt] = *(const half8*)&As[buf][row * BK + ((ck ^ (row & 7)) << 3)];
            }
#pragma unroll
            for (int nt = 0; nt < 2; ++nt) {
                int row = wn + nt * 16 + l16;
                b[nt] = *(const half8*)&Bs[buf][row * BK + ((ck ^ (row & 7)) << 3)];
            }
#pragma unroll
            for (int mt = 0; mt < 4; ++mt)
#pragma unroll
                for (int nt = 0; nt < 2; ++nt)
                    acc[mt][nt] = __builtin_amdgcn_mfma_f32_16x16x32_f16(
                        a[mt], b[nt], acc[mt][nt], 0, 0, 0);
        }
    };

    pf(0);
    stage(0);
    __syncthreads();

#pragma unroll 1
    for (int kt = 0; kt < NKT; ++kt) {
        const int buf = kt & 1;
        if (kt + 1 < NKT) {
            pf(kt + 1);
            compute(buf);
            stage(buf ^ 1);
            __syncthreads();
        } else {
            compute(buf);
        }
    }

#pragma unroll
    for (int nt = 0; nt < 2; ++nt) {
        int n = n0 + wn + nt * 16 + l16;
        float bv = bias[n];
#pragma unroll
        for (int mt = 0; mt < 4; ++mt) {
            int mb = m0 + wm + mt * 16 + quad * 4;
#pragma unroll
            for (int r = 0; r < 4; ++r)
                out[(size_t)(mb + r) * OUT_F + n] = acc[mt][nt][r] + bv;
        }
    }
}

extern "C" void kernel_launch(void* const* d_in, const int* in_sizes, int n_in,
                              void* d_out, int out_size, void* d_ws, size_t ws_size,
                              hipStream_t stream) {
    const float* x    = (const float*)d_in[0];
    const int*   qw   = (const int*)d_in[1];
    const float* scp  = (const float*)d_in[2];
    const float* zpp  = (const float*)d_in[3];
    const float* bias = (const float*)d_in[4];
    float* out = (float*)d_out;
    (void)in_sizes; (void)n_in; (void)out_size;

    const size_t need = (size_t)512 * IN_F * sizeof(_Float16); // 4 MB
    if (ws_size >= need) {
        _Float16* xt = (_Float16*)d_ws;
        cvt_xt<<<dim3(1024), dim3(256), 0, stream>>>(x, xt);
        qlin_mfma7<<<dim3(NBLK), dim3(256), 0, stream>>>(xt, qw, scp, zpp, bias, out);
    } else {
        qlin_mfma4<<<dim3(688), dim3(256), 0, stream>>>(x, qw, scp, zpp, bias, out);
    }
}